// Round 21
// baseline (322.662 us; speedup 1.0000x reference)
//
#include <hip/hip_runtime.h>
#include <hip/hip_cooperative_groups.h>
#include <hip/hip_fp16.h>
#include <math.h>

namespace cg = cooperative_groups;

#define NN 50000
#define FD 8
#define TD 12
#define HD 64
#define FT 96            // FD*TD halves per node
#define EE 1600000
#define NBUK 391         // ceil(NN/128) dst buckets of 128 nodes; also tile count
#define TILE2 4093       // ceil(EE/NBUK) edges per tile
#define SORTCAP 5120     // LDS staging cap per bucket (mean 4096, sigma 64 -> +16s)

// ws offsets (4B units)
#define OFF_BASE  512                    // int[NBUK+1]
#define OFF_CUR   1024                   // int[NBUK]
#define OFF_ROWST 2048                   // int[NN+1]
#define OFF_DINV  (2048 + NN + 16)       // float[NN]
#define OFF_FUSED (OFF_DINV + NN)        // float[1164]
#define OFF_THIST (OFF_FUSED + 1184)     // int[NBUK*NBUK] per-tile bucket counts
#define OFF_XH    (OFF_THIST + NBUK*NBUK + 16) // half[NN*FT] t-major
#define OFF_BEDGE (OFF_XH + NN*48)       // int2[EE] = 2*EE units
#define OFF_AGGH  (OFF_BEDGE + 2*EE)     // half[NN*FT] t-major
// total ~= 8.3M units ~= 33 MB

typedef _Float16 h2v __attribute__((ext_vector_type(2)));

__device__ inline void h8f(uint4 h, float* f) {
    const __half2* p = (const __half2*)&h;
#pragma unroll
    for (int i = 0; i < 4; ++i) {
        float2 v = __half22float2(p[i]);
        f[2 * i] = v.x; f[2 * i + 1] = v.y;
    }
}

__device__ inline uint4 f8h(const float* f) {
    uint4 o;
    __half2* p = (__half2*)&o;
#pragma unroll
    for (int i = 0; i < 4; ++i) p[i] = __floats2half2_rn(f[2 * i], f[2 * i + 1]);
    return o;
}

// Cooperative build: Phase1 hist(+precompute) -> Phase2 scan(+xhalf) ->
// Phase3 place (reuses phase-1 LDS histogram) -> Phase4 per-bucket sort.
// 392 blocks x 512 threads, all co-resident (47.7 KB LDS -> 3 blocks/CU).
__global__ __launch_bounds__(512) void k_build(const int* __restrict__ ei,
                                               const float* __restrict__ w,
                                               const float* __restrict__ x,
                                               int* __restrict__ thist,
                                               int* __restrict__ bktbase,
                                               int* __restrict__ cursor,
                                               int2* __restrict__ bedge,
                                               int* __restrict__ rowstart,
                                               float* __restrict__ dinv,
                                               uint4* __restrict__ xh4,
                                               const float* __restrict__ conv_w,
                                               const float* __restrict__ conv_b,
                                               const float* __restrict__ lin_w,
                                               const float* __restrict__ lin_b,
                                               const float* __restrict__ attention,
                                               float* __restrict__ fused) {
    __shared__ int h[NBUK];           // tile histogram; persists P1 -> P3
    __shared__ int bbase[NBUK];
    __shared__ int s[512];
    __shared__ int2 stage[SORTCAP];   // 40 KB (phase 4)
    __shared__ int cnt[128];
    __shared__ float wd[128];
    __shared__ int rowbase[128];
    cg::grid_group grid = cg::this_grid();
    int b = blockIdx.x, tid = threadIdx.x;

    // ---- Phase 1: per-tile histogram (0..390) | weight precompute (391) ----
    if (b < NBUK) {
        for (int i = tid; i < NBUK; i += 512) h[i] = 0;
        __syncthreads();
        int base = b * TILE2;
        int end = min(base + TILE2, EE);
        for (int e = base + tid; e < end; e += 512)
            atomicAdd(&h[ei[EE + e] >> 7], 1);
        __syncthreads();
        int* trow = thist + b * NBUK;
        for (int i = tid; i < NBUK; i += 512) trow[i] = h[i];
    } else {
        // Wzz (0..511), Whh (512..1023)
        for (int idx = tid; idx < 1024; idx += 512) {
            int sel = idx >> 9;
            int f = (idx & 511) >> 6;
            int hh = idx & 63;
            const float* cw = conv_w + f * 192 + (sel ? 128 : 0);
            const float* lw = lin_w + (sel ? 2 * 128 * 64 : 0) + hh;
            float sv = 0.f;
            for (int k = 0; k < 64; ++k) sv += cw[k] * lw[k * 64];
            fused[idx] = sv;
        }
        if (tid < 128) {
            int sel = tid >> 6;
            int hh = tid & 63;
            const float* cb = conv_b + (sel ? 128 : 0);
            const float* lw = lin_w + (sel ? 2 * 128 * 64 : 0) + hh;
            float sv = lin_b[(sel ? 2 * 64 : 0) + hh];
            for (int k = 0; k < 64; ++k) sv += cb[k] * lw[k * 64];
            fused[1024 + tid] = sv;
        }
        if (tid == 0) {
            float m = attention[0];
            for (int t = 1; t < TD; ++t) m = fmaxf(m, attention[t]);
            float e[TD], sum = 0.f;
            for (int t = 0; t < TD; ++t) { e[t] = __expf(attention[t] - m); sum += e[t]; }
            for (int t = 0; t < TD; ++t) fused[1152 + t] = e[t] / sum;
        }
    }
    grid.sync();

    // ---- Phase 2: scan (block 0) | x -> fp16 t-major transpose (1..390) ----
    if (b == 0) {
        int v = 0;
        if (tid < NBUK)
            for (int t = 0; t < NBUK; ++t) v += thist[t * NBUK + tid];
        s[tid] = v;
        __syncthreads();
        for (int off = 1; off < 512; off <<= 1) {
            int t = (tid >= off) ? s[tid - off] : 0;
            __syncthreads();
            s[tid] += t;
            __syncthreads();
        }
        int excl = s[tid] - v;
        if (tid < NBUK) { bktbase[tid] = excl; cursor[tid] = excl; }
        if (tid == NBUK - 1) bktbase[NBUK] = excl + v;   // == EE
    } else if (b <= 390) {
        unsigned g = (unsigned)(b - 1) * 512u + tid;
        for (unsigned i = g; i < (unsigned)NN * 12u; i += 390u * 512u) {
            unsigned n = i / 12u, t = i - n * 12u;
            const float* xp = x + (size_t)n * FT + t;
            float f[8];
#pragma unroll
            for (int k = 0; k < 8; ++k) f[k] = xp[k * 12];
            xh4[i] = f8h(f);
        }
    }
    grid.sync();

    // ---- Phase 3: place (0..390), claim via persisted LDS histogram ----
    if (b < NBUK) {
        for (int i = tid; i < NBUK; i += 512) {
            int c = h[i];
            bbase[i] = c ? atomicAdd(&cursor[i], c) : 0;
            h[i] = 0;                         // reuse as per-(tile,bucket) rank
        }
        __syncthreads();
        int base = b * TILE2;
        int end = min(base + TILE2, EE);
        for (int e = base + tid; e < end; e += 512) {
            int dst = ei[EE + e];
            int bk = dst >> 7;
            int rank = atomicAdd(&h[bk], 1);
            bedge[bbase[bk] + rank] =
                make_int2(ei[e] | ((dst & 127) << 16), __float_as_int(w[e]));
        }
    }
    grid.sync();

    // ---- Phase 4: per-bucket LDS counting sort (0..390) ----
    if (b < NBUK) {
        int es = bktbase[b], ee = bktbase[b + 1];
        int count = ee - es;
        if (count > SORTCAP) count = SORTCAP;   // statistically unreachable
        if (tid < 128) { cnt[tid] = 0; wd[tid] = 0.f; }
        __syncthreads();
        for (int i = tid; i < count; i += 512) {
            int2 u = bedge[es + i];
            stage[i] = u;
            int dl = u.x >> 16;
            atomicAdd(&cnt[dl], 1);
            atomicAdd(&wd[dl], __int_as_float(u.y));
        }
        __syncthreads();
        if (tid < 128) rowbase[tid] = cnt[tid];
        __syncthreads();
        for (int off = 1; off < 128; off <<= 1) {
            int t = 0;
            if (tid >= off && tid < 128) t = rowbase[tid - off];
            __syncthreads();
            if (tid < 128) rowbase[tid] += t;
            __syncthreads();
        }
        int dbase = b << 7;
        if (tid < 128) {
            int excl = rowbase[tid] - cnt[tid];
            rowbase[tid] = excl;
            if (dbase + tid < NN) {
                rowstart[dbase + tid] = es + excl;
                dinv[dbase + tid] = rsqrtf(1.0f + wd[tid]);   // self-loop weight 1
            }
            cnt[tid] = 0;   // reuse as per-dst rank cursor
        }
        if (b == NBUK - 1 && tid == 0) rowstart[NN] = ee;
        __syncthreads();
        for (int i = tid; i < count; i += 512) {
            int2 u = stage[i];
            int dl = u.x >> 16;
            int pos = atomicAdd(&cnt[dl], 1);
            bedge[es + rowbase[dl] + pos] = make_int2(u.x & 0xFFFF, u.y);
        }
    }
}

// thread = (node, uint4-chunk). 12 lanes/node. coeff = dinv[src]*w computed
// inline (dinv table L2-resident). 8 independent edge chains.
__global__ __launch_bounds__(256) void k_gather(const uint4* __restrict__ xh4,
                                                const float* __restrict__ dinv,
                                                const int* __restrict__ rowstart,
                                                const int2* __restrict__ edata,
                                                uint4* __restrict__ aggh) {
    unsigned t = blockIdx.x * 256u + threadIdx.x;
    if (t >= (unsigned)NN * 12u) return;
    unsigned n = t / 12u;
    unsigned c = t - n * 12u;
    float dv = dinv[n];
    float a[8];
    h8f(xh4[n * 12u + c], a);
#pragma unroll
    for (int j = 0; j < 8; ++j) a[j] *= dv;          // dinv[n]*x[n] (self-loop)
    int rs = rowstart[n], re = rowstart[n + 1];
    int k = rs;
    for (; k + 7 < re; k += 8) {                     // 8 independent chains
        int2 p[8];
#pragma unroll
        for (int q = 0; q < 8; ++q) p[q] = edata[k + q];
        float co[8];
#pragma unroll
        for (int q = 0; q < 8; ++q) co[q] = dinv[p[q].x] * __int_as_float(p[q].y);
        uint4 hv[8];
#pragma unroll
        for (int q = 0; q < 8; ++q) hv[q] = xh4[(unsigned)p[q].x * 12u + c];
#pragma unroll
        for (int q = 0; q < 8; ++q) {
            float v[8];
            h8f(hv[q], v);
#pragma unroll
            for (int j = 0; j < 8; ++j) a[j] += co[q] * v[j];
        }
    }
    for (; k < re; ++k) {
        int2 p = edata[k];
        float co = dinv[p.x] * __int_as_float(p.y);
        float v[8];
        h8f(xh4[(unsigned)p.x * 12u + c], v);
#pragma unroll
        for (int j = 0; j < 8; ++j) a[j] += co * v[j];
    }
#pragma unroll
    for (int j = 0; j < 8; ++j) a[j] *= dv;          // outer dinv[n]
    aggh[n * 12u + c] = f8h(a);
}

// h-per-lane GRU: lane = h, rcp gates, fp16 r consumed via v_dot2_f32_f16
// with fp16 weight pairs (R18-proven).
__global__ __launch_bounds__(256) void k_node(const uint4* __restrict__ aggh,
                                              const float* __restrict__ fused,
                                              const float* __restrict__ cls_w,
                                              const float* __restrict__ cls_b,
                                              float* __restrict__ out) {
    __shared__ uint4 r4_lds[32 * 12];     // 32 nodes x 12 t-chunks fp16, 6 KB
    __shared__ float rel_lds[32 * 68];    // [node][h], stride 68 (16B-aligned)
    __shared__ float cwT_lds[12 * 68];    // cw transposed [t][h], stride 68
    __shared__ float cb_lds[12];
    __shared__ float probs_lds[12];
    int tid = threadIdx.x;
    int nbase = blockIdx.x * 32;

    for (int id = tid; id < 384; id += 256) {
        int nl = id / 12, c = id - nl * 12;
        int n = nbase + nl;
        uint4 v = make_uint4(0, 0, 0, 0);
        if (n < NN) v = aggh[(size_t)n * 12 + c];
        r4_lds[nl * 12 + c] = v;
    }
    for (int id = tid; id < 768; id += 256) {
        int hh = id / 12, t = id - hh * 12;
        cwT_lds[t * 68 + hh] = cls_w[id];
    }
    if (tid < 12) { cb_lds[tid] = cls_b[tid]; probs_lds[tid] = fused[1152 + tid]; }

    int h = tid & 63;
    int w = tid >> 6;
    h2v wz2[4], wh2[4];
#pragma unroll
    for (int q = 0; q < 4; ++q) {
        wz2[q] = h2v{(_Float16)fused[(2 * q) * 64 + h],
                     (_Float16)fused[(2 * q + 1) * 64 + h]};
        wh2[q] = h2v{(_Float16)fused[512 + (2 * q) * 64 + h],
                     (_Float16)fused[512 + (2 * q + 1) * 64 + h]};
    }
    float bz = fused[1024 + h], bh = fused[1088 + h];
    __syncthreads();

#pragma unroll
    for (int np = 0; np < 4; ++np) {
        int nl0 = w * 8 + np * 2;
        const uint4* rp0 = &r4_lds[nl0 * 12];
        const uint4* rp1 = rp0 + 12;
        float acc0 = 0.f, acc1 = 0.f;
#pragma unroll
        for (int t = 0; t < TD; ++t) {
            uint4 u0 = rp0[t];               // 1 b128 broadcast per node,t
            uint4 u1 = rp1[t];
            const h2v* ra = (const h2v*)&u0;
            const h2v* rb = (const h2v*)&u1;
            float z0 = bz, h0 = bh, z1 = bz, h1 = bh;
#if defined(__has_builtin) && __has_builtin(__builtin_amdgcn_fdot2)
#pragma unroll
            for (int q = 0; q < 4; ++q) {
                z0 = __builtin_amdgcn_fdot2(ra[q], wz2[q], z0, false);
                h0 = __builtin_amdgcn_fdot2(ra[q], wh2[q], h0, false);
                z1 = __builtin_amdgcn_fdot2(rb[q], wz2[q], z1, false);
                h1 = __builtin_amdgcn_fdot2(rb[q], wh2[q], h1, false);
            }
#else
#pragma unroll
            for (int q = 0; q < 4; ++q) {
                z0 += (float)ra[q].x * (float)wz2[q].x + (float)ra[q].y * (float)wz2[q].y;
                h0 += (float)ra[q].x * (float)wh2[q].x + (float)ra[q].y * (float)wh2[q].y;
                z1 += (float)rb[q].x * (float)wz2[q].x + (float)rb[q].y * (float)wz2[q].y;
                h1 += (float)rb[q].x * (float)wh2[q].x + (float)rb[q].y * (float)wh2[q].y;
            }
#endif
            float om0 = __builtin_amdgcn_rcpf(1.f + __expf(z0));
            float om1 = __builtin_amdgcn_rcpf(1.f + __expf(z1));
            float Ht0 = 1.f - 2.f * __builtin_amdgcn_rcpf(1.f + __expf(2.f * h0));
            float Ht1 = 1.f - 2.f * __builtin_amdgcn_rcpf(1.f + __expf(2.f * h1));
            float p = probs_lds[t];
            acc0 += p * om0 * Ht0;
            acc1 += p * om1 * Ht1;
        }
        rel_lds[nl0 * 68 + h] = fmaxf(acc0, 0.f);
        rel_lds[(nl0 + 1) * 68 + h] = fmaxf(acc1, 0.f);
    }
    __syncthreads();

    for (int id = tid; id < 384; id += 256) {
        int nl = id / 12, t = id - nl * 12;
        int n = nbase + nl;
        if (n >= NN) continue;
        const float* rl = &rel_lds[nl * 68];
        const float* cwr = &cwT_lds[t * 68];
        float s = cb_lds[t];
#pragma unroll
        for (int k = 0; k < 16; ++k) {
            float4 rv = *(const float4*)&rl[k * 4];
            float4 cv = *(const float4*)&cwr[k * 4];
            s += rv.x * cv.x + rv.y * cv.y + rv.z * cv.z + rv.w * cv.w;
        }
        out[(size_t)n * TD + t] = s;
    }
}

extern "C" void kernel_launch(void* const* d_in, const int* in_sizes, int n_in,
                              void* d_out, int out_size, void* d_ws, size_t ws_size,
                              hipStream_t stream) {
    const float* x         = (const float*)d_in[0];
    const int*   ei        = (const int*)d_in[1];
    const float* w         = (const float*)d_in[2];
    const float* conv_w    = (const float*)d_in[3];
    const float* conv_b    = (const float*)d_in[4];
    const float* lin_w     = (const float*)d_in[5];
    const float* lin_b     = (const float*)d_in[6];
    const float* attention = (const float*)d_in[7];
    const float* cls_w     = (const float*)d_in[8];
    const float* cls_b     = (const float*)d_in[9];
    float* ws  = (float*)d_ws;
    float* out = (float*)d_out;

    int*   bktbase  = (int*)(ws + OFF_BASE);
    int*   cursor   = (int*)(ws + OFF_CUR);
    int*   rowstart = (int*)(ws + OFF_ROWST);
    float* dinv     = ws + OFF_DINV;
    float* fused    = ws + OFF_FUSED;
    int*   thist    = (int*)(ws + OFF_THIST);
    uint4* xh4      = (uint4*)(ws + OFF_XH);
    int2*  bedge    = (int2*)(ws + OFF_BEDGE);
    uint4* aggh     = (uint4*)(ws + OFF_AGGH);

    void* kargs[] = {(void*)&ei, (void*)&w, (void*)&x, (void*)&thist,
                     (void*)&bktbase, (void*)&cursor, (void*)&bedge,
                     (void*)&rowstart, (void*)&dinv, (void*)&xh4,
                     (void*)&conv_w, (void*)&conv_b, (void*)&lin_w,
                     (void*)&lin_b, (void*)&attention, (void*)&fused};
    hipLaunchCooperativeKernel((void*)k_build, dim3(NBUK + 1), dim3(512),
                               kargs, 0, stream);
    {
        unsigned total = (unsigned)NN * 12u;   // 600K threads
        k_gather<<<(total + 255) / 256, 256, 0, stream>>>(xh4, dinv,
                                                          rowstart, bedge, aggh);
    }
    k_node<<<(NN + 31) / 32, 256, 0, stream>>>(aggh, fused, cls_w, cls_b, out);
}

// Round 22
// 146.507 us; speedup vs baseline: 2.2024x; 2.2024x over previous
//
#include <hip/hip_runtime.h>
#include <hip/hip_fp16.h>
#include <math.h>

#define NN 50000
#define FD 8
#define TD 12
#define HD 64
#define FT 96            // FD*TD halves per node
#define EE 1600000
#define NBUK 391         // ceil(NN/128) dst buckets of 128 nodes
#define TILE 16384
#define NT 98            // ceil(EE/TILE)
#define XB2 1172         // ceil(NN*12/512) xhalf blocks (ride along k_sortx)
#define BSLOT 5120       // fixed slots per bucket (mean 4092, sigma 64 -> +16s)

// ws offsets (4B units)
#define OFF_CUR   0                      // int[512]
#define OFF_RS    512                    // int[NN] per-node edge range start
#define OFF_RE    (512 + NN)             // int[NN] per-node edge range end
#define OFF_DINV  (512 + 2*NN)           // float[NN]
#define OFF_FUSED (512 + 3*NN)           // float[1184]
#define OFF_XH    (OFF_FUSED + 1184)     // half[NN*FT] t-major (16B-aligned)
#define OFF_BEDGE (OFF_XH + NN*48)       // int2[NBUK*BSLOT]
#define OFF_AGGH  (OFF_BEDGE + 2*NBUK*BSLOT) // half[NN*FT] t-major
// total ~= 8.96M units ~= 35.8 MB (R4 already used this budget)

typedef _Float16 h2v __attribute__((ext_vector_type(2)));

__device__ inline void h8f(uint4 h, float* f) {
    const __half2* p = (const __half2*)&h;
#pragma unroll
    for (int i = 0; i < 4; ++i) {
        float2 v = __half22float2(p[i]);
        f[2 * i] = v.x; f[2 * i + 1] = v.y;
    }
}

__device__ inline uint4 f8h(const float* f) {
    uint4 o;
    __half2* p = (__half2*)&o;
#pragma unroll
    for (int i = 0; i < 4; ++i) p[i] = __floats2half2_rn(f[2 * i], f[2 * i + 1]);
    return o;
}

// cursor init (fixed per-bucket slot bases) + weight-fusion precompute
__global__ __launch_bounds__(512) void k_init(int* __restrict__ cursor,
                                              const float* __restrict__ conv_w,
                                              const float* __restrict__ conv_b,
                                              const float* __restrict__ lin_w,
                                              const float* __restrict__ lin_b,
                                              const float* __restrict__ attention,
                                              float* __restrict__ fused) {
    int tid = threadIdx.x;
    if (tid < NBUK) cursor[tid] = tid * BSLOT;
    // Wzz (0..511), Whh (512..1023)
    for (int idx = tid; idx < 1024; idx += 512) {
        int sel = idx >> 9;
        int f = (idx & 511) >> 6;
        int h = idx & 63;
        const float* cw = conv_w + f * 192 + (sel ? 128 : 0);
        const float* lw = lin_w + (sel ? 2 * 128 * 64 : 0) + h;
        float s = 0.f;
        for (int k = 0; k < 64; ++k) s += cw[k] * lw[k * 64];
        fused[idx] = s;
    }
    if (tid < 128) {
        int sel = tid >> 6;
        int h = tid & 63;
        const float* cb = conv_b + (sel ? 128 : 0);
        const float* lw = lin_w + (sel ? 2 * 128 * 64 : 0) + h;
        float s = lin_b[(sel ? 2 * 64 : 0) + h];
        for (int k = 0; k < 64; ++k) s += cb[k] * lw[k * 64];
        fused[1024 + tid] = s;
    }
    if (tid == 0) {
        float m = attention[0];
        for (int t = 1; t < TD; ++t) m = fmaxf(m, attention[t]);
        float e[TD], sum = 0.f;
        for (int t = 0; t < TD; ++t) { e[t] = __expf(attention[t] - m); sum += e[t]; }
        for (int t = 0; t < TD; ++t) fused[1152 + t] = e[t] / sum;
    }
}

// fused hist+claim+write per tile: LDS histogram of this tile's dsts, claim
// per-bucket ranges from global cursors (fixed slot bases), write packed edges
// grouped by bucket: (src|dst_local<<16, w). No global scan needed.
__global__ __launch_bounds__(1024) void k_place2(const int* __restrict__ ei,
                                                 const float* __restrict__ w,
                                                 int* __restrict__ cursor,
                                                 int2* __restrict__ bedge) {
    __shared__ int h[NBUK], bbase[NBUK];
    int tid = threadIdx.x;
    for (int i = tid; i < NBUK; i += 1024) h[i] = 0;
    __syncthreads();
    int base = blockIdx.x * TILE;
    for (int i = 0; i < TILE / 1024; ++i) {
        int e = base + i * 1024 + tid;
        if (e < EE) atomicAdd(&h[ei[EE + e] >> 7], 1);
    }
    __syncthreads();
    for (int i = tid; i < NBUK; i += 1024) {
        int c = h[i];
        bbase[i] = c ? atomicAdd(&cursor[i], c) : 0;
        h[i] = 0;                             // reuse as per-(tile,bucket) rank
    }
    __syncthreads();
    for (int i = 0; i < TILE / 1024; ++i) {
        int e = base + i * 1024 + tid;
        if (e < EE) {
            int dst = ei[EE + e];             // L2-hot (2nd read)
            int bk = dst >> 7;
            int rank = atomicAdd(&h[bk], 1);
            bedge[bbase[bk] + rank] =
                make_int2(ei[e] | ((dst & 127) << 16), __float_as_int(w[e]));
        }
    }
}

// blocks [0,NBUK): per-bucket LDS counting sort in place within the bucket's
// fixed slot region [b*BSLOT, cursor[b]); emits per-node rs/re + dinv.
// blocks [NBUK,NBUK+XB2): x (f-major fp32) -> xh (t-major fp16) transpose.
__global__ __launch_bounds__(512) void k_sortx(const int* __restrict__ cursor,
                                               int2* __restrict__ bedge,
                                               int* __restrict__ rs,
                                               int* __restrict__ re_,
                                               float* __restrict__ dinv,
                                               const float* __restrict__ x,
                                               uint4* __restrict__ xh4) {
    __shared__ int2 stage[BSLOT];     // 40 KB
    __shared__ int cnt[128];
    __shared__ float wd[128];
    __shared__ int rowbase[128];
    int tid = threadIdx.x, b = blockIdx.x;
    if (b >= NBUK) {
        unsigned i = (unsigned)(b - NBUK) * 512u + tid;
        if (i < (unsigned)NN * 12u) {
            unsigned n = i / 12u, t = i - n * 12u;
            const float* xp = x + (size_t)n * FT + t;
            float f[8];
#pragma unroll
            for (int k = 0; k < 8; ++k) f[k] = xp[k * 12];
            xh4[i] = f8h(f);
        }
        return;
    }
    int es = b * BSLOT;
    int count = cursor[b] - es;               // bucket size (< BSLOT by 16-sigma)
    if (count > BSLOT) count = BSLOT;
    if (tid < 128) { cnt[tid] = 0; wd[tid] = 0.f; }
    __syncthreads();
    for (int i = tid; i < count; i += 512) {
        int2 u = bedge[es + i];
        stage[i] = u;
        int dl = u.x >> 16;
        atomicAdd(&cnt[dl], 1);
        atomicAdd(&wd[dl], __int_as_float(u.y));
    }
    __syncthreads();
    if (tid < 128) rowbase[tid] = cnt[tid];
    __syncthreads();
    for (int off = 1; off < 128; off <<= 1) {
        int t = 0;
        if (tid >= off && tid < 128) t = rowbase[tid - off];
        __syncthreads();
        if (tid < 128) rowbase[tid] += t;
        __syncthreads();
    }
    int dbase = b << 7;
    if (tid < 128) {
        int cv = cnt[tid];
        int excl = rowbase[tid] - cv;
        rowbase[tid] = excl;
        if (dbase + tid < NN) {
            rs[dbase + tid] = es + excl;
            re_[dbase + tid] = es + excl + cv;
            dinv[dbase + tid] = rsqrtf(1.0f + wd[tid]);   // self-loop weight 1
        }
        cnt[tid] = 0;   // reuse as per-dst rank cursor
    }
    __syncthreads();
    for (int i = tid; i < count; i += 512) {
        int2 u = stage[i];
        int dl = u.x >> 16;
        int pos = atomicAdd(&cnt[dl], 1);
        bedge[es + rowbase[dl] + pos] = make_int2(u.x & 0xFFFF, u.y);
    }
}

// thread = (node, uint4-chunk). 12 lanes/node. coeff = dinv[src]*w computed
// inline (dinv table L2-resident). 8 independent edge chains.
__global__ __launch_bounds__(256) void k_gather(const uint4* __restrict__ xh4,
                                                const float* __restrict__ dinv,
                                                const int* __restrict__ rs,
                                                const int* __restrict__ re_,
                                                const int2* __restrict__ edata,
                                                uint4* __restrict__ aggh) {
    unsigned t = blockIdx.x * 256u + threadIdx.x;
    if (t >= (unsigned)NN * 12u) return;
    unsigned n = t / 12u;
    unsigned c = t - n * 12u;
    float dv = dinv[n];
    float a[8];
    h8f(xh4[n * 12u + c], a);
#pragma unroll
    for (int j = 0; j < 8; ++j) a[j] *= dv;          // dinv[n]*x[n] (self-loop)
    int k = rs[n], re = re_[n];
    for (; k + 7 < re; k += 8) {                     // 8 independent chains
        int2 p[8];
#pragma unroll
        for (int q = 0; q < 8; ++q) p[q] = edata[k + q];
        float co[8];
#pragma unroll
        for (int q = 0; q < 8; ++q) co[q] = dinv[p[q].x] * __int_as_float(p[q].y);
        uint4 hv[8];
#pragma unroll
        for (int q = 0; q < 8; ++q) hv[q] = xh4[(unsigned)p[q].x * 12u + c];
#pragma unroll
        for (int q = 0; q < 8; ++q) {
            float v[8];
            h8f(hv[q], v);
#pragma unroll
            for (int j = 0; j < 8; ++j) a[j] += co[q] * v[j];
        }
    }
    for (; k < re; ++k) {
        int2 p = edata[k];
        float co = dinv[p.x] * __int_as_float(p.y);
        float v[8];
        h8f(xh4[(unsigned)p.x * 12u + c], v);
#pragma unroll
        for (int j = 0; j < 8; ++j) a[j] += co * v[j];
    }
#pragma unroll
    for (int j = 0; j < 8; ++j) a[j] *= dv;          // outer dinv[n]
    aggh[n * 12u + c] = f8h(a);
}

// h-per-lane GRU: lane = h, rcp gates, fp16 r consumed via v_dot2_f32_f16
// with fp16 weight pairs (R18-proven).
__global__ __launch_bounds__(256) void k_node(const uint4* __restrict__ aggh,
                                              const float* __restrict__ fused,
                                              const float* __restrict__ cls_w,
                                              const float* __restrict__ cls_b,
                                              float* __restrict__ out) {
    __shared__ uint4 r4_lds[32 * 12];     // 32 nodes x 12 t-chunks fp16, 6 KB
    __shared__ float rel_lds[32 * 68];    // [node][h], stride 68 (16B-aligned)
    __shared__ float cwT_lds[12 * 68];    // cw transposed [t][h], stride 68
    __shared__ float cb_lds[12];
    __shared__ float probs_lds[12];
    int tid = threadIdx.x;
    int nbase = blockIdx.x * 32;

    for (int id = tid; id < 384; id += 256) {
        int nl = id / 12, c = id - nl * 12;
        int n = nbase + nl;
        uint4 v = make_uint4(0, 0, 0, 0);
        if (n < NN) v = aggh[(size_t)n * 12 + c];
        r4_lds[nl * 12 + c] = v;
    }
    for (int id = tid; id < 768; id += 256) {
        int hh = id / 12, t = id - hh * 12;
        cwT_lds[t * 68 + hh] = cls_w[id];
    }
    if (tid < 12) { cb_lds[tid] = cls_b[tid]; probs_lds[tid] = fused[1152 + tid]; }

    int h = tid & 63;
    int w = tid >> 6;
    h2v wz2[4], wh2[4];
#pragma unroll
    for (int q = 0; q < 4; ++q) {
        wz2[q] = h2v{(_Float16)fused[(2 * q) * 64 + h],
                     (_Float16)fused[(2 * q + 1) * 64 + h]};
        wh2[q] = h2v{(_Float16)fused[512 + (2 * q) * 64 + h],
                     (_Float16)fused[512 + (2 * q + 1) * 64 + h]};
    }
    float bz = fused[1024 + h], bh = fused[1088 + h];
    __syncthreads();

#pragma unroll
    for (int np = 0; np < 4; ++np) {
        int nl0 = w * 8 + np * 2;
        const uint4* rp0 = &r4_lds[nl0 * 12];
        const uint4* rp1 = rp0 + 12;
        float acc0 = 0.f, acc1 = 0.f;
#pragma unroll
        for (int t = 0; t < TD; ++t) {
            uint4 u0 = rp0[t];               // 1 b128 broadcast per node,t
            uint4 u1 = rp1[t];
            const h2v* ra = (const h2v*)&u0;
            const h2v* rb = (const h2v*)&u1;
            float z0 = bz, h0 = bh, z1 = bz, h1 = bh;
#if defined(__has_builtin) && __has_builtin(__builtin_amdgcn_fdot2)
#pragma unroll
            for (int q = 0; q < 4; ++q) {
                z0 = __builtin_amdgcn_fdot2(ra[q], wz2[q], z0, false);
                h0 = __builtin_amdgcn_fdot2(ra[q], wh2[q], h0, false);
                z1 = __builtin_amdgcn_fdot2(rb[q], wz2[q], z1, false);
                h1 = __builtin_amdgcn_fdot2(rb[q], wh2[q], h1, false);
            }
#else
#pragma unroll
            for (int q = 0; q < 4; ++q) {
                z0 += (float)ra[q].x * (float)wz2[q].x + (float)ra[q].y * (float)wz2[q].y;
                h0 += (float)ra[q].x * (float)wh2[q].x + (float)ra[q].y * (float)wh2[q].y;
                z1 += (float)rb[q].x * (float)wz2[q].x + (float)rb[q].y * (float)wz2[q].y;
                h1 += (float)rb[q].x * (float)wh2[q].x + (float)rb[q].y * (float)wh2[q].y;
            }
#endif
            float om0 = __builtin_amdgcn_rcpf(1.f + __expf(z0));
            float om1 = __builtin_amdgcn_rcpf(1.f + __expf(z1));
            float Ht0 = 1.f - 2.f * __builtin_amdgcn_rcpf(1.f + __expf(2.f * h0));
            float Ht1 = 1.f - 2.f * __builtin_amdgcn_rcpf(1.f + __expf(2.f * h1));
            float p = probs_lds[t];
            acc0 += p * om0 * Ht0;
            acc1 += p * om1 * Ht1;
        }
        rel_lds[nl0 * 68 + h] = fmaxf(acc0, 0.f);
        rel_lds[(nl0 + 1) * 68 + h] = fmaxf(acc1, 0.f);
    }
    __syncthreads();

    for (int id = tid; id < 384; id += 256) {
        int nl = id / 12, t = id - nl * 12;
        int n = nbase + nl;
        if (n >= NN) continue;
        const float* rl = &rel_lds[nl * 68];
        const float* cwr = &cwT_lds[t * 68];
        float s = cb_lds[t];
#pragma unroll
        for (int k = 0; k < 16; ++k) {
            float4 rv = *(const float4*)&rl[k * 4];
            float4 cv = *(const float4*)&cwr[k * 4];
            s += rv.x * cv.x + rv.y * cv.y + rv.z * cv.z + rv.w * cv.w;
        }
        out[(size_t)n * TD + t] = s;
    }
}

extern "C" void kernel_launch(void* const* d_in, const int* in_sizes, int n_in,
                              void* d_out, int out_size, void* d_ws, size_t ws_size,
                              hipStream_t stream) {
    const float* x         = (const float*)d_in[0];
    const int*   ei        = (const int*)d_in[1];
    const float* w         = (const float*)d_in[2];
    const float* conv_w    = (const float*)d_in[3];
    const float* conv_b    = (const float*)d_in[4];
    const float* lin_w     = (const float*)d_in[5];
    const float* lin_b     = (const float*)d_in[6];
    const float* attention = (const float*)d_in[7];
    const float* cls_w     = (const float*)d_in[8];
    const float* cls_b     = (const float*)d_in[9];
    float* ws  = (float*)d_ws;
    float* out = (float*)d_out;

    int*   cursor   = (int*)(ws + OFF_CUR);
    int*   rs       = (int*)(ws + OFF_RS);
    int*   re_      = (int*)(ws + OFF_RE);
    float* dinv     = ws + OFF_DINV;
    float* fused    = ws + OFF_FUSED;
    uint4* xh4      = (uint4*)(ws + OFF_XH);
    int2*  bedge    = (int2*)(ws + OFF_BEDGE);
    uint4* aggh     = (uint4*)(ws + OFF_AGGH);

    k_init<<<1, 512, 0, stream>>>(cursor, conv_w, conv_b, lin_w, lin_b,
                                  attention, fused);
    k_place2<<<NT, 1024, 0, stream>>>(ei, w, cursor, bedge);
    k_sortx<<<NBUK + XB2, 512, 0, stream>>>(cursor, bedge, rs, re_, dinv, x, xh4);
    {
        unsigned total = (unsigned)NN * 12u;   // 600K threads
        k_gather<<<(total + 255) / 256, 256, 0, stream>>>(xh4, dinv, rs, re_,
                                                          bedge, aggh);
    }
    k_node<<<(NN + 31) / 32, 256, 0, stream>>>(aggh, fused, cls_w, cls_b, out);
}

// Round 23
// 145.861 us; speedup vs baseline: 2.2121x; 1.0044x over previous
//
#include <hip/hip_runtime.h>
#include <hip/hip_fp16.h>
#include <math.h>

#define NN 50000
#define FD 8
#define TD 12
#define HD 64
#define FT 96            // FD*TD halves per node
#define EE 1600000
#define NBUK 391         // ceil(NN/128) dst buckets of 128 nodes
#define TILE 16384
#define NT 98            // ceil(EE/TILE)
#define XB2 1172         // ceil(NN*12/512) xhalf blocks (ride along k_sortx)
#define BSLOT 5120       // fixed slots per bucket (mean 4092, sigma 64 -> +16s)

// ws offsets (4B units)
#define OFF_CUR   0                      // int[512] (relative counts, memset to 0)
#define OFF_RS    512                    // int[NN] per-node edge range start
#define OFF_RE    (512 + NN)             // int[NN] per-node edge range end
#define OFF_DINV  (512 + 2*NN)           // float[NN]
#define OFF_FUSED (512 + 3*NN)           // float[1184]
#define OFF_XH    (OFF_FUSED + 1184)     // half[NN*FT] t-major (16B-aligned)
#define OFF_BEDGE (OFF_XH + NN*48)       // int2[NBUK*BSLOT]
#define OFF_AGGH  (OFF_BEDGE + 2*NBUK*BSLOT) // half[NN*FT] t-major
// total ~= 8.96M units ~= 35.8 MB

typedef _Float16 h2v __attribute__((ext_vector_type(2)));

__device__ inline void h8f(uint4 h, float* f) {
    const __half2* p = (const __half2*)&h;
#pragma unroll
    for (int i = 0; i < 4; ++i) {
        float2 v = __half22float2(p[i]);
        f[2 * i] = v.x; f[2 * i + 1] = v.y;
    }
}

__device__ inline uint4 f8h(const float* f) {
    uint4 o;
    __half2* p = (__half2*)&o;
#pragma unroll
    for (int i = 0; i < 4; ++i) p[i] = __floats2half2_rn(f[2 * i], f[2 * i + 1]);
    return o;
}

// blocks [0,NT): fused hist+claim+write per tile (relative cursors, fixed
// bucket bases b*BSLOT). block NT: weight-fusion precompute (independent).
__global__ __launch_bounds__(1024) void k_place2(const int* __restrict__ ei,
                                                 const float* __restrict__ w,
                                                 int* __restrict__ cursor,
                                                 int2* __restrict__ bedge,
                                                 const float* __restrict__ conv_w,
                                                 const float* __restrict__ conv_b,
                                                 const float* __restrict__ lin_w,
                                                 const float* __restrict__ lin_b,
                                                 const float* __restrict__ attention,
                                                 float* __restrict__ fused) {
    int tid = threadIdx.x;
    if (blockIdx.x == NT) {
        // ---- weight fusion: Wzz (0..511), Whh (512..1023) ----
        if (tid < 1024) {
            int sel = tid >> 9;
            int f = (tid & 511) >> 6;
            int h = tid & 63;
            const float* cw = conv_w + f * 192 + (sel ? 128 : 0);
            const float* lw = lin_w + (sel ? 2 * 128 * 64 : 0) + h;
            float s = 0.f;
            for (int k = 0; k < 64; ++k) s += cw[k] * lw[k * 64];
            fused[tid] = s;
        }
        if (tid < 128) {
            int sel = tid >> 6;
            int h = tid & 63;
            const float* cb = conv_b + (sel ? 128 : 0);
            const float* lw = lin_w + (sel ? 2 * 128 * 64 : 0) + h;
            float s = lin_b[(sel ? 2 * 64 : 0) + h];
            for (int k = 0; k < 64; ++k) s += cb[k] * lw[k * 64];
            fused[1024 + tid] = s;
        }
        if (tid == 0) {
            float m = attention[0];
            for (int t = 1; t < TD; ++t) m = fmaxf(m, attention[t]);
            float e[TD], sum = 0.f;
            for (int t = 0; t < TD; ++t) { e[t] = __expf(attention[t] - m); sum += e[t]; }
            for (int t = 0; t < TD; ++t) fused[1152 + t] = e[t] / sum;
        }
        return;
    }
    __shared__ int h[NBUK], bbase[NBUK];
    for (int i = tid; i < NBUK; i += 1024) h[i] = 0;
    __syncthreads();
    int base = blockIdx.x * TILE;
    for (int i = 0; i < TILE / 1024; ++i) {
        int e = base + i * 1024 + tid;
        if (e < EE) atomicAdd(&h[ei[EE + e] >> 7], 1);
    }
    __syncthreads();
    for (int i = tid; i < NBUK; i += 1024) {
        int c = h[i];
        bbase[i] = c ? (i * BSLOT + atomicAdd(&cursor[i], c)) : 0;
        h[i] = 0;                             // reuse as per-(tile,bucket) rank
    }
    __syncthreads();
    for (int i = 0; i < TILE / 1024; ++i) {
        int e = base + i * 1024 + tid;
        if (e < EE) {
            int dst = ei[EE + e];             // L2-hot (2nd read)
            int bk = dst >> 7;
            int rank = atomicAdd(&h[bk], 1);
            bedge[bbase[bk] + rank] =
                make_int2(ei[e] | ((dst & 127) << 16), __float_as_int(w[e]));
        }
    }
}

// blocks [0,NBUK): per-bucket LDS counting sort in place within the bucket's
// fixed slot region [b*BSLOT, b*BSLOT+cursor[b]); emits per-node rs/re + dinv.
// blocks [NBUK,NBUK+XB2): x (f-major fp32) -> xh (t-major fp16) transpose.
__global__ __launch_bounds__(512) void k_sortx(const int* __restrict__ cursor,
                                               int2* __restrict__ bedge,
                                               int* __restrict__ rs,
                                               int* __restrict__ re_,
                                               float* __restrict__ dinv,
                                               const float* __restrict__ x,
                                               uint4* __restrict__ xh4) {
    __shared__ int2 stage[BSLOT];     // 40 KB
    __shared__ int cnt[128];
    __shared__ float wd[128];
    __shared__ int rowbase[128];
    int tid = threadIdx.x, b = blockIdx.x;
    if (b >= NBUK) {
        unsigned i = (unsigned)(b - NBUK) * 512u + tid;
        if (i < (unsigned)NN * 12u) {
            unsigned n = i / 12u, t = i - n * 12u;
            const float* xp = x + (size_t)n * FT + t;
            float f[8];
#pragma unroll
            for (int k = 0; k < 8; ++k) f[k] = xp[k * 12];
            xh4[i] = f8h(f);
        }
        return;
    }
    int es = b * BSLOT;
    int count = cursor[b];                    // bucket size (< BSLOT by 16-sigma)
    if (count > BSLOT) count = BSLOT;
    if (tid < 128) { cnt[tid] = 0; wd[tid] = 0.f; }
    __syncthreads();
    for (int i = tid; i < count; i += 512) {
        int2 u = bedge[es + i];
        stage[i] = u;
        int dl = u.x >> 16;
        atomicAdd(&cnt[dl], 1);
        atomicAdd(&wd[dl], __int_as_float(u.y));
    }
    __syncthreads();
    if (tid < 128) rowbase[tid] = cnt[tid];
    __syncthreads();
    for (int off = 1; off < 128; off <<= 1) {
        int t = 0;
        if (tid >= off && tid < 128) t = rowbase[tid - off];
        __syncthreads();
        if (tid < 128) rowbase[tid] += t;
        __syncthreads();
    }
    int dbase = b << 7;
    if (tid < 128) {
        int cv = cnt[tid];
        int excl = rowbase[tid] - cv;
        rowbase[tid] = excl;
        if (dbase + tid < NN) {
            rs[dbase + tid] = es + excl;
            re_[dbase + tid] = es + excl + cv;
            dinv[dbase + tid] = rsqrtf(1.0f + wd[tid]);   // self-loop weight 1
        }
        cnt[tid] = 0;   // reuse as per-dst rank cursor
    }
    __syncthreads();
    for (int i = tid; i < count; i += 512) {
        int2 u = stage[i];
        int dl = u.x >> 16;
        int pos = atomicAdd(&cnt[dl], 1);
        bedge[es + rowbase[dl] + pos] = make_int2(u.x & 0xFFFF, u.y);
    }
}

// thread = (node, uint4-chunk). 12 lanes/node. coeff = dinv[src]*w computed
// inline (dinv table L2-resident). 8 independent edge chains.
__global__ __launch_bounds__(256) void k_gather(const uint4* __restrict__ xh4,
                                                const float* __restrict__ dinv,
                                                const int* __restrict__ rs,
                                                const int* __restrict__ re_,
                                                const int2* __restrict__ edata,
                                                uint4* __restrict__ aggh) {
    unsigned t = blockIdx.x * 256u + threadIdx.x;
    if (t >= (unsigned)NN * 12u) return;
    unsigned n = t / 12u;
    unsigned c = t - n * 12u;
    float dv = dinv[n];
    float a[8];
    h8f(xh4[n * 12u + c], a);
#pragma unroll
    for (int j = 0; j < 8; ++j) a[j] *= dv;          // dinv[n]*x[n] (self-loop)
    int k = rs[n], re = re_[n];
    for (; k + 7 < re; k += 8) {                     // 8 independent chains
        int2 p[8];
#pragma unroll
        for (int q = 0; q < 8; ++q) p[q] = edata[k + q];
        float co[8];
#pragma unroll
        for (int q = 0; q < 8; ++q) co[q] = dinv[p[q].x] * __int_as_float(p[q].y);
        uint4 hv[8];
#pragma unroll
        for (int q = 0; q < 8; ++q) hv[q] = xh4[(unsigned)p[q].x * 12u + c];
#pragma unroll
        for (int q = 0; q < 8; ++q) {
            float v[8];
            h8f(hv[q], v);
#pragma unroll
            for (int j = 0; j < 8; ++j) a[j] += co[q] * v[j];
        }
    }
    for (; k < re; ++k) {
        int2 p = edata[k];
        float co = dinv[p.x] * __int_as_float(p.y);
        float v[8];
        h8f(xh4[(unsigned)p.x * 12u + c], v);
#pragma unroll
        for (int j = 0; j < 8; ++j) a[j] += co * v[j];
    }
#pragma unroll
    for (int j = 0; j < 8; ++j) a[j] *= dv;          // outer dinv[n]
    aggh[n * 12u + c] = f8h(a);
}

// h-per-lane GRU: lane = h, rcp gates, fp16 r consumed via v_dot2_f32_f16
// with fp16 weight pairs (R18-proven).
__global__ __launch_bounds__(256) void k_node(const uint4* __restrict__ aggh,
                                              const float* __restrict__ fused,
                                              const float* __restrict__ cls_w,
                                              const float* __restrict__ cls_b,
                                              float* __restrict__ out) {
    __shared__ uint4 r4_lds[32 * 12];     // 32 nodes x 12 t-chunks fp16, 6 KB
    __shared__ float rel_lds[32 * 68];    // [node][h], stride 68 (16B-aligned)
    __shared__ float cwT_lds[12 * 68];    // cw transposed [t][h], stride 68
    __shared__ float cb_lds[12];
    __shared__ float probs_lds[12];
    int tid = threadIdx.x;
    int nbase = blockIdx.x * 32;

    for (int id = tid; id < 384; id += 256) {
        int nl = id / 12, c = id - nl * 12;
        int n = nbase + nl;
        uint4 v = make_uint4(0, 0, 0, 0);
        if (n < NN) v = aggh[(size_t)n * 12 + c];
        r4_lds[nl * 12 + c] = v;
    }
    for (int id = tid; id < 768; id += 256) {
        int hh = id / 12, t = id - hh * 12;
        cwT_lds[t * 68 + hh] = cls_w[id];
    }
    if (tid < 12) { cb_lds[tid] = cls_b[tid]; probs_lds[tid] = fused[1152 + tid]; }

    int h = tid & 63;
    int w = tid >> 6;
    h2v wz2[4], wh2[4];
#pragma unroll
    for (int q = 0; q < 4; ++q) {
        wz2[q] = h2v{(_Float16)fused[(2 * q) * 64 + h],
                     (_Float16)fused[(2 * q + 1) * 64 + h]};
        wh2[q] = h2v{(_Float16)fused[512 + (2 * q) * 64 + h],
                     (_Float16)fused[512 + (2 * q + 1) * 64 + h]};
    }
    float bz = fused[1024 + h], bh = fused[1088 + h];
    __syncthreads();

#pragma unroll
    for (int np = 0; np < 4; ++np) {
        int nl0 = w * 8 + np * 2;
        const uint4* rp0 = &r4_lds[nl0 * 12];
        const uint4* rp1 = rp0 + 12;
        float acc0 = 0.f, acc1 = 0.f;
#pragma unroll
        for (int t = 0; t < TD; ++t) {
            uint4 u0 = rp0[t];               // 1 b128 broadcast per node,t
            uint4 u1 = rp1[t];
            const h2v* ra = (const h2v*)&u0;
            const h2v* rb = (const h2v*)&u1;
            float z0 = bz, h0 = bh, z1 = bz, h1 = bh;
#if defined(__has_builtin) && __has_builtin(__builtin_amdgcn_fdot2)
#pragma unroll
            for (int q = 0; q < 4; ++q) {
                z0 = __builtin_amdgcn_fdot2(ra[q], wz2[q], z0, false);
                h0 = __builtin_amdgcn_fdot2(ra[q], wh2[q], h0, false);
                z1 = __builtin_amdgcn_fdot2(rb[q], wz2[q], z1, false);
                h1 = __builtin_amdgcn_fdot2(rb[q], wh2[q], h1, false);
            }
#else
#pragma unroll
            for (int q = 0; q < 4; ++q) {
                z0 += (float)ra[q].x * (float)wz2[q].x + (float)ra[q].y * (float)wz2[q].y;
                h0 += (float)ra[q].x * (float)wh2[q].x + (float)ra[q].y * (float)wh2[q].y;
                z1 += (float)rb[q].x * (float)wz2[q].x + (float)rb[q].y * (float)wz2[q].y;
                h1 += (float)rb[q].x * (float)wh2[q].x + (float)rb[q].y * (float)wh2[q].y;
            }
#endif
            float om0 = __builtin_amdgcn_rcpf(1.f + __expf(z0));
            float om1 = __builtin_amdgcn_rcpf(1.f + __expf(z1));
            float Ht0 = 1.f - 2.f * __builtin_amdgcn_rcpf(1.f + __expf(2.f * h0));
            float Ht1 = 1.f - 2.f * __builtin_amdgcn_rcpf(1.f + __expf(2.f * h1));
            float p = probs_lds[t];
            acc0 += p * om0 * Ht0;
            acc1 += p * om1 * Ht1;
        }
        rel_lds[nl0 * 68 + h] = fmaxf(acc0, 0.f);
        rel_lds[(nl0 + 1) * 68 + h] = fmaxf(acc1, 0.f);
    }
    __syncthreads();

    for (int id = tid; id < 384; id += 256) {
        int nl = id / 12, t = id - nl * 12;
        int n = nbase + nl;
        if (n >= NN) continue;
        const float* rl = &rel_lds[nl * 68];
        const float* cwr = &cwT_lds[t * 68];
        float s = cb_lds[t];
#pragma unroll
        for (int k = 0; k < 16; ++k) {
            float4 rv = *(const float4*)&rl[k * 4];
            float4 cv = *(const float4*)&cwr[k * 4];
            s += rv.x * cv.x + rv.y * cv.y + rv.z * cv.z + rv.w * cv.w;
        }
        out[(size_t)n * TD + t] = s;
    }
}

extern "C" void kernel_launch(void* const* d_in, const int* in_sizes, int n_in,
                              void* d_out, int out_size, void* d_ws, size_t ws_size,
                              hipStream_t stream) {
    const float* x         = (const float*)d_in[0];
    const int*   ei        = (const int*)d_in[1];
    const float* w         = (const float*)d_in[2];
    const float* conv_w    = (const float*)d_in[3];
    const float* conv_b    = (const float*)d_in[4];
    const float* lin_w     = (const float*)d_in[5];
    const float* lin_b     = (const float*)d_in[6];
    const float* attention = (const float*)d_in[7];
    const float* cls_w     = (const float*)d_in[8];
    const float* cls_b     = (const float*)d_in[9];
    float* ws  = (float*)d_ws;
    float* out = (float*)d_out;

    int*   cursor   = (int*)(ws + OFF_CUR);
    int*   rs       = (int*)(ws + OFF_RS);
    int*   re_      = (int*)(ws + OFF_RE);
    float* dinv     = ws + OFF_DINV;
    float* fused    = ws + OFF_FUSED;
    uint4* xh4      = (uint4*)(ws + OFF_XH);
    int2*  bedge    = (int2*)(ws + OFF_BEDGE);
    uint4* aggh     = (uint4*)(ws + OFF_AGGH);

    hipMemsetAsync(cursor, 0, NBUK * sizeof(int), stream);
    k_place2<<<NT + 1, 1024, 0, stream>>>(ei, w, cursor, bedge,
                                          conv_w, conv_b, lin_w, lin_b,
                                          attention, fused);
    k_sortx<<<NBUK + XB2, 512, 0, stream>>>(cursor, bedge, rs, re_, dinv, x, xh4);
    {
        unsigned total = (unsigned)NN * 12u;   // 600K threads
        k_gather<<<(total + 255) / 256, 256, 0, stream>>>(xh4, dinv, rs, re_,
                                                          bedge, aggh);
    }
    k_node<<<(NN + 31) / 32, 256, 0, stream>>>(aggh, fused, cls_w, cls_b, out);
}